// Round 5
// baseline (3490.780 us; speedup 1.0000x reference)
//
#include <hip/hip_runtime.h>

#define HH   51
#define H4   204
#define TSEQ 2048
#define FUT  64
#define TT   (TSEQ + FUT)   // 2112
#define RPB  16             // batch rows per block (2 blocks/CU)
#define NTH  896            // 14 waves: 0..12 MFMA+act, 13 emit + x-prefetch
#define HSTR 72             // halfs per hbuf row (144 B stride: 16B-aligned, conflict-free b128)

typedef _Float16 h8 __attribute__((ext_vector_type(8)));
typedef float    f4 __attribute__((ext_vector_type(4)));

#define LOG2E 1.44269504f

__device__ __forceinline__ float sigm_f(float z) {
    return __builtin_amdgcn_rcpf(1.0f + __builtin_amdgcn_exp2f(-LOG2E * z));
}
__device__ __forceinline__ float tanh_f(float z) {
    return __builtin_fmaf(2.0f,
        __builtin_amdgcn_rcpf(1.0f + __builtin_amdgcn_exp2f(-2.0f * LOG2E * z)), -1.0f);
}

__global__ __launch_bounds__(NTH, 7)
void lstm_kernel(const float* __restrict__ x,
                 const float* __restrict__ Wih1, const float* __restrict__ Whh1,
                 const float* __restrict__ bih1, const float* __restrict__ bhh1,
                 const float* __restrict__ Wih2, const float* __restrict__ Whh2,
                 const float* __restrict__ bih2, const float* __restrict__ bhh2,
                 const float* __restrict__ Wout, const float* __restrict__ bout,
                 float* __restrict__ out)
{
    // double-buffered B-operand: [buf][row][k]; k=0: x_t, 1..51: h1, 52,53: const 1 (bias hi/lo)
    __shared__ _Float16 hbuf[2][RPB][HSTR];
    // per-wave partial sums of wout.h2, double-buffered: [buf][wave][row]
    __shared__ float part[2][13][17];
    __shared__ float wouts[64];

    const int tid  = threadIdx.x;
    const int lane = tid & 63;
    const int w    = tid >> 6;        // wave id 0..13
    const int quad = lane >> 4;       // 0..3
    const int nl   = lane & 15;       // batch row (B-operand n / C-D col)
    const int rb   = blockIdx.x * RPB;

    // ---------------- one-time init ----------------
    if (tid < 64) wouts[tid] = (tid < HH) ? Wout[tid] : 0.0f;
    for (int i = tid; i < 2 * RPB * HSTR; i += NTH) (&hbuf[0][0][0])[i] = (_Float16)0.0f;
    __syncthreads();
    if (tid < RPB) {
        hbuf[0][tid][0]  = (_Float16)x[(size_t)(rb + tid) * TSEQ];
        hbuf[0][tid][52] = (_Float16)1.0f;  hbuf[0][tid][53] = (_Float16)1.0f;
        hbuf[1][tid][52] = (_Float16)1.0f;  hbuf[1][tid][53] = (_Float16)1.0f;
    }
    const float bo = bout[0];

    // ---------------- weight A-fragments in registers (once) ----------------
    // wave w<13 owns gate m-tile w: rows j' = 16w..16w+15 (j' = 4k+q interleave)
    // A[m][k]: m = lane&15 -> j' = 16w+nl, k = 32s + quad*8 + j
    h8 W1[2], W2[2];
    if (w < 13) {
        const int jp = 16 * w + nl;
        const int kk = jp >> 2, q = jp & 3;
        const bool valid = (jp < H4);
        const int jrow = q * HH + kk;        // original gate row
        float b1 = 0.0f, b2 = 0.0f;
        if (valid) { b1 = bih1[jrow] + bhh1[jrow]; b2 = bih2[jrow] + bhh2[jrow]; }
        const _Float16 b1h = (_Float16)b1, b2h = (_Float16)b2;
        const _Float16 b1l = (_Float16)(b1 - (float)b1h), b2l = (_Float16)(b2 - (float)b2h);
        #pragma unroll
        for (int s = 0; s < 2; ++s) {
            h8 w1v, w2v;
            #pragma unroll
            for (int j = 0; j < 8; ++j) {
                const int k = s * 32 + quad * 8 + j;
                _Float16 a1 = (_Float16)0.0f, a2 = (_Float16)0.0f;
                if (valid) {
                    if (k == 0) {
                        a1 = (_Float16)Wih1[jrow];
                    } else if (k <= HH) {
                        const int o = jrow * HH + (k - 1);
                        a1 = (_Float16)Whh1[o];
                        a2 = (_Float16)(Wih2[o] + Whh2[o]);
                    } else if (k == 52) { a1 = b1h; a2 = b2h; }
                    else if (k == 53)   { a1 = b1l; a2 = b2l; }
                }
                w1v[j] = a1;
                w2v[j] = a2;
            }
            W1[s] = w1v;
            W2[s] = w2v;
        }
    }

    const int kh = 4 * w + quad;          // element k owned by this lane (w<13)
    const size_t obase = (size_t)(rb + (lane & 15)) * TT;    // wave-13 out base
    const size_t xbase = (size_t)(rb + (lane & 15)) * TSEQ;  // wave-13 x base
    float xnext = 0.0f;
    if (w == 13 && lane < RPB) xnext = x[xbase + 1];
    float c1 = 0.0f;
    __syncthreads();
    const float wk = (w < 13) ? wouts[kh] : 0.0f;   // wouts[51] = 0 masks invalid lane

    // ================= main sequence: ONE barrier phase per step =================
    // step t computes L1(t) AND the deferred emit L2(t-1) on the same B-fragments
    // (W2's k=0 weight is 0, so x_t in slot 0 doesn't pollute g2(t-1)).
    for (int t = 0; t < TSEQ; ++t) {
        const int cur = t & 1, nxt = cur ^ 1;
        if (w < 13) {
            const _Float16* hb = &hbuf[cur][nl][0];
            const h8 Bh0 = *(const h8*)(hb + quad * 8);
            const h8 Bh1 = *(const h8*)(hb + 32 + quad * 8);
            f4 g1 = {0.f, 0.f, 0.f, 0.f}, g2 = {0.f, 0.f, 0.f, 0.f};
            g1 = __builtin_amdgcn_mfma_f32_16x16x32_f16(W1[0], Bh0, g1, 0, 0, 0);
            g1 = __builtin_amdgcn_mfma_f32_16x16x32_f16(W1[1], Bh1, g1, 0, 0, 0);
            g2 = __builtin_amdgcn_mfma_f32_16x16x32_f16(W2[0], Bh0, g2, 0, 0, 0);
            g2 = __builtin_amdgcn_mfma_f32_16x16x32_f16(W2[1], Bh1, g2, 0, 0, 0);
            const float c_prev = c1;
            // ---- L1(t): update c, write h1(t) (critical path) ----
            {
                const float ig = sigm_f(g1[0]);
                const float fg = sigm_f(g1[1]);
                const float gg = tanh_f(g1[2]);
                const float og = sigm_f(g1[3]);
                c1 = fg * c1 + ig * gg;
                const float h1v = og * tanh_f(c1);
                if (kh < HH) hbuf[nxt][nl][1 + kh] = (_Float16)h1v;
            }
            // ---- deferred emit L2(t-1) with c1(t-1) (off critical path) ----
            {
                const float ig = sigm_f(g2[0]);
                const float fg = sigm_f(g2[1]);
                const float gg = tanh_f(g2[2]);
                const float og = sigm_f(g2[3]);
                const float c2 = fg * c_prev + ig * gg;
                float p = og * tanh_f(c2) * wk;
                p += __shfl_xor(p, 16, 64);          // reduce over quad (k within wave)
                p += __shfl_xor(p, 32, 64);
                if (quad == 0) part[cur][w][nl] = p;
            }
        } else if (lane < RPB) {                     // wave 13: emit out(t-2) + x pipeline
            if (t >= 2) {
                float s = bo;
                #pragma unroll
                for (int j = 0; j < 13; ++j) s += part[nxt][j][lane];
                out[obase + (t - 2)] = s;
            }
            if (t + 1 < TSEQ) hbuf[nxt][lane][0] = (_Float16)xnext;
            if (t + 2 < TSEQ) xnext = x[xbase + (t + 2)];
        }
        __syncthreads();
    }

    // ================= boundary flush: emit(2047) partials, out(2046), out(2047)+feedback =================
    // after main loop: h1(2047) in hbuf[0], c1 == c1(2047), part[1] == emit(2046) partials
    if (w < 13) {
        const _Float16* hb = &hbuf[0][nl][0];
        const h8 Bh0 = *(const h8*)(hb + quad * 8);
        const h8 Bh1 = *(const h8*)(hb + 32 + quad * 8);
        f4 g2 = {0.f, 0.f, 0.f, 0.f};
        g2 = __builtin_amdgcn_mfma_f32_16x16x32_f16(W2[0], Bh0, g2, 0, 0, 0);
        g2 = __builtin_amdgcn_mfma_f32_16x16x32_f16(W2[1], Bh1, g2, 0, 0, 0);
        const float ig = sigm_f(g2[0]);
        const float fg = sigm_f(g2[1]);
        const float gg = tanh_f(g2[2]);
        const float og = sigm_f(g2[3]);
        const float c2 = fg * c1 + ig * gg;
        float p = og * tanh_f(c2) * wk;
        p += __shfl_xor(p, 16, 64);
        p += __shfl_xor(p, 32, 64);
        if (quad == 0) part[0][w][nl] = p;
    } else if (lane < RPB) {
        float s = bo;
        #pragma unroll
        for (int j = 0; j < 13; ++j) s += part[1][j][lane];
        out[obase + (TSEQ - 2)] = s;
    }
    __syncthreads();
    if (w == 13 && lane < RPB) {
        float s = bo;
        #pragma unroll
        for (int j = 0; j < 13; ++j) s += part[0][j][lane];
        out[obase + (TSEQ - 1)] = s;
        hbuf[0][lane][0] = (_Float16)s;              // x input for first future step
    }
    __syncthreads();

    // ================= future steps: serial (feedback on critical path) =================
    for (int t = TSEQ; t < TT; ++t) {
        const int cur = t & 1, nxt = cur ^ 1;        // t=2048 -> cur=0: matches hbuf[0]
        if (w < 13) {
            const _Float16* hb = &hbuf[cur][nl][0];
            const h8 Bh0 = *(const h8*)(hb + quad * 8);
            const h8 Bh1 = *(const h8*)(hb + 32 + quad * 8);
            f4 g1 = {0.f, 0.f, 0.f, 0.f};
            g1 = __builtin_amdgcn_mfma_f32_16x16x32_f16(W1[0], Bh0, g1, 0, 0, 0);
            g1 = __builtin_amdgcn_mfma_f32_16x16x32_f16(W1[1], Bh1, g1, 0, 0, 0);
            const float ig = sigm_f(g1[0]);
            const float fg = sigm_f(g1[1]);
            const float gg = tanh_f(g1[2]);
            const float og = sigm_f(g1[3]);
            c1 = fg * c1 + ig * gg;
            const float h1v = og * tanh_f(c1);
            if (kh < HH) hbuf[nxt][nl][1 + kh] = (_Float16)h1v;
        }
        __syncthreads();
        if (w < 13) {
            const _Float16* hb = &hbuf[nxt][nl][0];  // h1(t) in slots 1..51; slot 0 stale (W2 ignores)
            const h8 Bh0 = *(const h8*)(hb + quad * 8);
            const h8 Bh1 = *(const h8*)(hb + 32 + quad * 8);
            f4 g2 = {0.f, 0.f, 0.f, 0.f};
            g2 = __builtin_amdgcn_mfma_f32_16x16x32_f16(W2[0], Bh0, g2, 0, 0, 0);
            g2 = __builtin_amdgcn_mfma_f32_16x16x32_f16(W2[1], Bh1, g2, 0, 0, 0);
            const float ig = sigm_f(g2[0]);
            const float fg = sigm_f(g2[1]);
            const float gg = tanh_f(g2[2]);
            const float og = sigm_f(g2[3]);
            const float c2 = fg * c1 + ig * gg;
            float p = og * tanh_f(c2) * wk;
            p += __shfl_xor(p, 16, 64);
            p += __shfl_xor(p, 32, 64);
            if (quad == 0) part[cur][w][nl] = p;
        }
        __syncthreads();
        if (w == 13 && lane < RPB) {
            float s = bo;
            #pragma unroll
            for (int j = 0; j < 13; ++j) s += part[cur][j][lane];
            out[obase + t] = s;
            if (t + 1 < TT) hbuf[nxt][lane][0] = (_Float16)s;   // autoregressive feedback
        }
        __syncthreads();
    }
}

extern "C" void kernel_launch(void* const* d_in, const int* in_sizes, int n_in,
                              void* d_out, int out_size, void* d_ws, size_t ws_size,
                              hipStream_t stream) {
    (void)in_sizes; (void)n_in; (void)d_ws; (void)ws_size; (void)out_size;
    const float* x    = (const float*)d_in[0];
    const float* Wih1 = (const float*)d_in[1];
    const float* Whh1 = (const float*)d_in[2];
    const float* bih1 = (const float*)d_in[3];
    const float* bhh1 = (const float*)d_in[4];
    const float* Wih2 = (const float*)d_in[5];
    const float* Whh2 = (const float*)d_in[6];
    const float* bih2 = (const float*)d_in[7];
    const float* bhh2 = (const float*)d_in[8];
    const float* Wout = (const float*)d_in[9];
    const float* bout = (const float*)d_in[10];
    float* outp = (float*)d_out;

    dim3 grid(8192 / RPB);   // 512 blocks, 2 per CU
    dim3 block(NTH);
    hipLaunchKernelGGL(lstm_kernel, grid, block, 0, stream,
                       x, Wih1, Whh1, bih1, bhh1, Wih2, Whh2, bih2, bhh2,
                       Wout, bout, outp);
}